// Round 7
// baseline (681.935 us; speedup 1.0000x reference)
//
#include <hip/hip_runtime.h>
#include <hip/hip_fp16.h>
#include <cstdint>

// Shapes (hard-coded): B=4, Cx=512, Cy=256, M=64, H=W=64, N=4096
constexpr int N_ = 4096;
constexpr float CNT = 16384.f;  // B*N reduction count for BN stats

typedef __attribute__((ext_vector_type(8))) _Float16 half8;
typedef __attribute__((ext_vector_type(4))) float f32x4;
union fragh { half8 h8; int i4[4]; };

__device__ inline int pkh(float a, float b) {
  union { __half2 h; int i; } u;
  u.h = __float22half2_rn(float2{a, b});
  return u.i;
}
// split-fp16 (Markidis): h = rn(a,b) packed; l = rn(residuals) packed
__device__ inline void pk_hl(float a, float b, int& h, int& l) {
  __half ah = __float2half_rn(a), bh = __float2half_rn(b);
  union { __half2 v; int i; } u;
  u.v = __halves2half2(ah, bh);
  h = u.i;
  float ar = a - __half2float(ah), br = b - __half2float(bh);
  union { __half2 v; int i; } w2;
  w2.v = __float22half2_rn(float2{ar, br});
  l = w2.i;
}
__device__ inline float2 uph(int v) {
  union { __half2 h; int i; } u;
  u.i = v;
  return float2{__half2float(__low2half(u.h)), __half2float(__high2half(u.h))};
}

// Stats layout (floats): group g in {0:s1,1:x1,2:y1,3:s2,4:x2,5:y2}:
//   sum at g*128+c, sumsq at g*128+64+c (c<64). f_up: sum 768+c, sumsq 1280+c.
//
// Fragment layouts (validated r6, correctness held):
//  B-operand frag buffer (activations): int at
//    ((((bIdx*KT + kt)*256 + ntg)*64 + q*16 + la)*4 + jj)
//    holds fp16 pair (k = kt*32 + q*8 + 2jj, k+1) at col n = ntg*16 + la.
//    hi array then lo array (offset = total hi ints).
//  A-operand frag buffer (weights): int at (((otg*KT + kt)*64 + q*16+la)*4 + jj)
//    holds pair (k...) of W[o = otg*16 + la].
//
// Workspace aliasing (stream-ordered):
//  z1f  w[0..3M)   frag hi/lo per branch (1M ints each: hi .5M | lo .5M)
//  z2f  w[3..6M)   same; Afy aliases w[3..7M) (dead before conv2/attn write)
//  foutf w[6..7M)  frag hi/lo over m-pairs (attn -> convup), 1M ints
//  u    w[7..15M)  fp32; Afx aliases it (dead before convup writes)
//  Qf/Kf/Vf at w+15M; stats; wt1f/wt2f/biasf/wuf at tail

// ---------------- packA: x,y -> B-fragment hi/lo fp16 ------------------------------
__global__ __launch_bounds__(256) void packA_k(const float* __restrict__ x,
                                               const float* __restrict__ y,
                                               int* __restrict__ Afx,
                                               int* __restrict__ Afy) {
  const int job = blockIdx.y;
  if (job == 1 && blockIdx.x >= 2048) return;
  const int idx = blockIdx.x * 256 + threadIdx.x;
  const float* src = job ? y : x;
  int* dst = job ? Afy : Afx;
  const int KT = job ? 8 : 16;
  const int loOff = job ? 2097152 : 4194304;
  const int n = idx & 4095, q = (idx >> 12) & 3;
  const int kt = job ? ((idx >> 14) & 7) : ((idx >> 14) & 15);
  const int b = job ? (idx >> 17) : (idx >> 18);
  const float* sp = src + ((size_t)(b * (KT * 32) + kt * 32 + q * 8)) * N_ + n;
  float a[8];
#pragma unroll
  for (int j = 0; j < 8; ++j) a[j] = sp[(size_t)j * N_];
  int4 hi, lo;
  pk_hl(a[0], a[1], hi.x, lo.x);
  pk_hl(a[2], a[3], hi.y, lo.y);
  pk_hl(a[4], a[5], hi.z, lo.z);
  pk_hl(a[6], a[7], hi.w, lo.w);
  const int base = (((b * KT + kt) * 256 + (n >> 4)) * 64 + q * 16 + (n & 15)) * 4;
  *(int4*)&dst[base] = hi;
  *(int4*)&dst[loOff + base] = lo;
}

// ---------------- prep1: stage-1 weights -> A-fragment hi/lo -----------------------
__global__ __launch_bounds__(256) void prep1_k(const float* __restrict__ ws1,
                                               const float* __restrict__ wx1,
                                               const float* __restrict__ wy1,
                                               int* __restrict__ wt1f) {
  const int idx = blockIdx.x * 256 + threadIdx.x;  // 0..40959
  const float* W;
  int KT, K, hiBase, loOff, e;
  if (idx < 16384) { W = ws1; KT = 16; K = 512; hiBase = 0; loOff = 16384; e = idx; }
  else if (idx < 32768) { W = wx1; KT = 16; K = 512; hiBase = 32768; loOff = 16384; e = idx - 16384; }
  else { W = wy1; KT = 8; K = 256; hiBase = 65536; loOff = 8192; e = idx - 32768; }
  const int jj = e & 3, lane = (e >> 2) & 63;
  int kt, ot;
  if (KT == 16) { kt = (e >> 8) & 15; ot = e >> 12; } else { kt = (e >> 8) & 7; ot = e >> 11; }
  const int o = ot * 16 + (lane & 15);
  const int k = kt * 32 + (lane >> 4) * 8 + 2 * jj;
  int h, l;
  pk_hl(W[o * K + k], W[o * K + k + 1], h, l);
  wt1f[hiBase + e] = h;
  wt1f[hiBase + loOff + e] = l;
}

// ---------------- prep2: fold BN1 into stage-2 weights -> A-frag hi/lo + bias ------
__global__ __launch_bounds__(256) void prep2_k(
    const float* __restrict__ ws2, const float* __restrict__ wx2,
    const float* __restrict__ wy2,
    const float* __restrict__ gs1, const float* __restrict__ bs1,
    const float* __restrict__ gx1, const float* __restrict__ bx1,
    const float* __restrict__ gy1, const float* __restrict__ by1,
    const float* __restrict__ stats, int* __restrict__ wt2f,
    float* __restrict__ biasf) {
  const int branch = blockIdx.x;
  const int t = threadIdx.x;
  const float* W = branch == 0 ? ws2 : (branch == 1 ? wx2 : wy2);
  const float* g1 = branch == 0 ? gs1 : (branch == 1 ? gx1 : gy1);
  const float* b1 = branch == 0 ? bs1 : (branch == 1 ? bx1 : by1);
  const float* stin = stats + branch * 128;
  int* outW = wt2f + branch * 4096;

  auto scale = [&](int k) {
    float mean = stin[k] * (1.f / CNT);
    float var = stin[64 + k] * (1.f / CNT) - mean * mean;
    return g1[k] * rsqrtf(var + 1e-5f);
  };
#pragma unroll
  for (int i = 0; i < 8; ++i) {
    int e = i * 256 + t;
    int jj = e & 3, lane = (e >> 2) & 63, kt = (e >> 8) & 1, ot = e >> 9;
    int o = ot * 16 + (lane & 15);
    int k = kt * 32 + (lane >> 4) * 8 + 2 * jj;
    float w0 = W[o * 64 + k] * scale(k);
    float w1 = W[o * 64 + k + 1] * scale(k + 1);
    int h, l;
    pk_hl(w0, w1, h, l);
    outW[e] = h;
    outW[2048 + e] = l;
  }
  if (t < 64) {
    float s = 0.f;
    for (int k = 0; k < 64; ++k) {
      float mean = stin[k] * (1.f / CNT);
      float var = stin[64 + k] * (1.f / CNT) - mean * mean;
      float sc = g1[k] * rsqrtf(var + 1e-5f);
      float sh = b1[k] - mean * sc;
      s += W[t * 64 + k] * sh;
    }
    biasf[branch * 64 + t] = s;
  }
}

// ---------------- prep_up: f_up weights -> A-frag hi/lo (otg in [0,32)) ------------
__global__ __launch_bounds__(256) void prepu_k(const float* __restrict__ wu,
                                               int* __restrict__ wuf) {
  const int e = blockIdx.x * 256 + threadIdx.x;  // 0..16383
  const int jj = e & 3, lane = (e >> 2) & 63, kt = (e >> 8) & 1, otg = e >> 9;
  const int o = otg * 16 + (lane & 15);
  const int m = kt * 32 + (lane >> 4) * 8 + 2 * jj;
  int h, l;
  pk_hl(wu[o * 64 + m], wu[o * 64 + m + 1], h, l);
  wuf[e] = h;
  wuf[16384 + e] = l;
}

// ---------------- stage-1 convs: split-fp16 MFMA, prefetch double-buffer -----------
// 1 ntg per wave -> grid 768 blocks (3/CU, 3 waves/SIMD). 2-step unrolled K-loop
// with named A/B frag buffers (static indexing): loads for kt+1 issued before the
// MFMAs of kt, so HBM latency hides under compute + TLP.
__global__ __launch_bounds__(256) void conv1_k(
    const int* __restrict__ Afx, const int* __restrict__ Afy,
    const int* __restrict__ wt1f, int* __restrict__ z1f,
    float* __restrict__ stats) {
  const int t = threadIdx.x;
  const int lane = t & 63;
  const int wv = t >> 6;
  const int la = lane & 15;
  const int quad = lane >> 4;
  const int b = blockIdx.x >> 6;
  const int ns = blockIdx.x & 63;
  const int branch = blockIdx.y;
  const int KT = branch == 2 ? 8 : 16;
  const int* Af = branch == 2 ? Afy : Afx;
  const int aLo = branch == 2 ? 2097152 : 4194304;
  const int* Wf = wt1f + (branch == 0 ? 0 : (branch == 1 ? 32768 : 65536));
  const int wLo = branch == 2 ? 8192 : 16384;
  float* st = stats + branch * 128;
  int* zb = z1f + branch * 1048576;
  const int ntg0 = ns * 4 + wv;

  f32x4 acc[4];
#pragma unroll
  for (int ot = 0; ot < 4; ++ot) acc[ot] = f32x4{0.f, 0.f, 0.f, 0.f};

  auto loadF = [&](int kt, fragh (&wh)[4], fragh (&wl)[4], fragh& ah, fragh& al) {
#pragma unroll
    for (int ot = 0; ot < 4; ++ot) {
      const int base = ((ot * KT + kt) * 64 + lane) * 4;
      *(int4*)wh[ot].i4 = *(const int4*)&Wf[base];
      *(int4*)wl[ot].i4 = *(const int4*)&Wf[wLo + base];
    }
    const int abase = (((b * KT + kt) * 256 + ntg0) * 64 + lane) * 4;
    *(int4*)ah.i4 = *(const int4*)&Af[abase];
    *(int4*)al.i4 = *(const int4*)&Af[aLo + abase];
  };
  auto mm = [&](fragh (&wh)[4], fragh (&wl)[4], fragh& ah, fragh& al) {
#pragma unroll
    for (int ot = 0; ot < 4; ++ot) {
      acc[ot] = __builtin_amdgcn_mfma_f32_16x16x32_f16(wh[ot].h8, ah.h8, acc[ot], 0, 0, 0);
      acc[ot] = __builtin_amdgcn_mfma_f32_16x16x32_f16(wh[ot].h8, al.h8, acc[ot], 0, 0, 0);
      acc[ot] = __builtin_amdgcn_mfma_f32_16x16x32_f16(wl[ot].h8, ah.h8, acc[ot], 0, 0, 0);
    }
  };

  fragh whA[4], wlA[4], ahA, alA;
  fragh whB[4], wlB[4], ahB, alB;
  loadF(0, whA, wlA, ahA, alA);
#pragma unroll 1
  for (int kt = 0; kt < KT; kt += 2) {
    loadF(kt + 1, whB, wlB, ahB, alB);
    mm(whA, wlA, ahA, alA);
    if (kt + 2 < KT) loadF(kt + 2, whA, wlA, ahA, alA);
    mm(whB, wlB, ahB, alB);
  }

  // z1 frag write: o = ot*16+quad*4+r, pairs (r0,r1),(r2,r3) are in-lane
#pragma unroll
  for (int ot = 0; ot < 4; ++ot) {
    const int ktz = ot >> 1;
    const int qz = (ot & 1) * 2 + (quad >> 1);
    const int jz = (quad & 1) * 2;
    const int addr = (((b * 2 + ktz) * 256 + ntg0) * 64 + qz * 16 + la) * 4 + jz;
    int h0, l0, h1, l1;
    pk_hl(acc[ot][0], acc[ot][1], h0, l0);
    pk_hl(acc[ot][2], acc[ot][3], h1, l1);
    *(int2*)&zb[addr] = int2{h0, h1};
    *(int2*)&zb[524288 + addr] = int2{l0, l1};
  }
#pragma unroll
  for (int ot = 0; ot < 4; ++ot)
#pragma unroll
    for (int r = 0; r < 4; ++r) {
      float s = acc[ot][r];
      float q = s * s;
#pragma unroll
      for (int d = 1; d < 16; d <<= 1) { s += __shfl_xor(s, d); q += __shfl_xor(q, d); }
      if (la == 0) {
        atomicAdd(&st[ot * 16 + quad * 4 + r], s);
        atomicAdd(&st[64 + ot * 16 + quad * 4 + r], q);
      }
    }
}

// ---------------- stage-2 convs: split-fp16 MFMA, prefetch, BN1 pre-folded ---------
__global__ __launch_bounds__(256) void conv2_k(
    const int* __restrict__ z1f, const int* __restrict__ wt2f,
    const float* __restrict__ biasf, int* __restrict__ z2f,
    float* __restrict__ stats) {
  const int t = threadIdx.x;
  const int lane = t & 63;
  const int wv = t >> 6;
  const int la = lane & 15;
  const int quad = lane >> 4;
  const int b = blockIdx.x >> 6;
  const int ns = blockIdx.x & 63;
  const int branch = blockIdx.y;
  const int* Af = z1f + branch * 1048576;
  const int* Wf = wt2f + branch * 4096;
  const float* bias = biasf + branch * 64;
  float* st = stats + (3 + branch) * 128;
  int* zb = z2f + branch * 1048576;
  const int ntg0 = ns * 4 + wv;

  f32x4 acc[4];
#pragma unroll
  for (int ot = 0; ot < 4; ++ot) {
#pragma unroll
    for (int r = 0; r < 4; ++r) acc[ot][r] = bias[ot * 16 + quad * 4 + r];
  }

  auto loadF = [&](int kt, fragh (&wh)[4], fragh (&wl)[4], fragh& ah, fragh& al) {
#pragma unroll
    for (int ot = 0; ot < 4; ++ot) {
      const int base = ((ot * 2 + kt) * 64 + lane) * 4;
      *(int4*)wh[ot].i4 = *(const int4*)&Wf[base];
      *(int4*)wl[ot].i4 = *(const int4*)&Wf[2048 + base];
    }
    const int abase = (((b * 2 + kt) * 256 + ntg0) * 64 + lane) * 4;
    *(int4*)ah.i4 = *(const int4*)&Af[abase];
    *(int4*)al.i4 = *(const int4*)&Af[524288 + abase];
  };
  auto mm = [&](fragh (&wh)[4], fragh (&wl)[4], fragh& ah, fragh& al) {
#pragma unroll
    for (int ot = 0; ot < 4; ++ot) {
      acc[ot] = __builtin_amdgcn_mfma_f32_16x16x32_f16(wh[ot].h8, ah.h8, acc[ot], 0, 0, 0);
      acc[ot] = __builtin_amdgcn_mfma_f32_16x16x32_f16(wh[ot].h8, al.h8, acc[ot], 0, 0, 0);
      acc[ot] = __builtin_amdgcn_mfma_f32_16x16x32_f16(wl[ot].h8, ah.h8, acc[ot], 0, 0, 0);
    }
  };

  fragh whA[4], wlA[4], ahA, alA;
  fragh whB[4], wlB[4], ahB, alB;
  loadF(0, whA, wlA, ahA, alA);
  loadF(1, whB, wlB, ahB, alB);
  mm(whA, wlA, ahA, alA);
  mm(whB, wlB, ahB, alB);

#pragma unroll
  for (int ot = 0; ot < 4; ++ot) {
    const int ktz = ot >> 1;
    const int qz = (ot & 1) * 2 + (quad >> 1);
    const int jz = (quad & 1) * 2;
    const int addr = (((b * 2 + ktz) * 256 + ntg0) * 64 + qz * 16 + la) * 4 + jz;
    int h0, l0, h1, l1;
    pk_hl(acc[ot][0], acc[ot][1], h0, l0);
    pk_hl(acc[ot][2], acc[ot][3], h1, l1);
    *(int2*)&zb[addr] = int2{h0, h1};
    *(int2*)&zb[524288 + addr] = int2{l0, l1};
  }
#pragma unroll
  for (int ot = 0; ot < 4; ++ot)
#pragma unroll
    for (int r = 0; r < 4; ++r) {
      float s = acc[ot][r];
      float q = s * s;
#pragma unroll
      for (int d = 1; d < 16; d <<= 1) { s += __shfl_xor(s, d); q += __shfl_xor(q, d); }
      if (la == 0) {
        atomicAdd(&st[ot * 16 + quad * 4 + r], s);
        atomicAdd(&st[64 + ot * 16 + quad * 4 + r], q);
      }
    }
}

// ---------------- pack Q/K/V from frag-format z2 with inline BN2 -------------------
__global__ __launch_bounds__(256) void pack_k(
    const int* __restrict__ z2f,
    const float* __restrict__ gs2, const float* __restrict__ bs2,
    const float* __restrict__ gx2, const float* __restrict__ bx2,
    const float* __restrict__ gy2, const float* __restrict__ by2,
    int* __restrict__ Qf, int* __restrict__ Kf, int* __restrict__ Vf,
    const float* __restrict__ stats) {
  const int job = blockIdx.z;  // 0: Q<-x2, 1: K<-y2, 2: V<-s2
  const int idx = blockIdx.x * 256 + threadIdx.x;
  const float* g2 = job == 0 ? gx2 : (job == 1 ? gy2 : gs2);
  const float* b2 = job == 0 ? bx2 : (job == 1 ? by2 : bs2);
  const float* st = stats + (job == 0 ? 4 : (job == 1 ? 5 : 3)) * 128;

  auto snorm = [&](int c, float& s, float& h) {
    float mean = st[c] * (1.f / CNT);
    float var = st[64 + c] * (1.f / CNT) - mean * mean;
    float r = rsqrtf(var + 1e-5f);
    s = g2[c] * r;
    h = b2[c] - mean * s;
  };
  if (job < 2) {
    const int* zf = z2f + (job == 0 ? 1048576 : 2097152);
    int* outp = job == 0 ? Qf : Kf;
    int h = zf[idx], l = zf[524288 + idx];
    int jj = idx & 3, lane = (idx >> 2) & 63, q = lane >> 4;
    int kt = (idx >> 16) & 1;
    int c0 = 2 * (kt * 16 + q * 4 + jj);
    float s0, h0, s1, h1;
    snorm(c0, s0, h0);
    snorm(c0 + 1, s1, h1);
    float2 vh = uph(h), vl = uph(l);
    outp[idx] = pkh((vh.x + vl.x) * s0 + h0, (vh.y + vl.y) * s1 + h1);
  } else {
    int w_ = idx & 3, lane = (idx >> 2) & 63, la_v = lane & 15, q_v = lane >> 4;
    int mt = (idx >> 8) & 3, kb = (idx >> 10) & 127, b = idx >> 17;
    int ch = mt * 16 + la_v;
    int k = kb * 16 + q_v * 4 + w_;
    int n0 = 2 * k;
    int kp = ch >> 1, kt = kp >> 4, qz = (kp >> 2) & 3, jz = kp & 3, half = ch & 1;
    int a0 = (((b * 2 + kt) * 256 + (n0 >> 4)) * 64 + qz * 16 + (n0 & 15)) * 4 + jz;
    float2 h0v = uph(z2f[a0]), l0v = uph(z2f[524288 + a0]);
    float2 h1v = uph(z2f[a0 + 4]), l1v = uph(z2f[524288 + a0 + 4]);
    float v0 = half ? (h0v.y + l0v.y) : (h0v.x + l0v.x);
    float v1 = half ? (h1v.y + l1v.y) : (h1v.x + l1v.x);
    float s0, h0;
    snorm(ch, s0, h0);
    Vf[idx] = pkh(v0 * s0 + h0, v1 * s0 + h0);
  }
}

// ---------------- MFMA fp16 flash attention; epilogue emits fout as B-frag hi/lo ---
__global__ __launch_bounds__(256, 4) void attn_k(const int* __restrict__ Qf,
                                                 const int* __restrict__ Kf,
                                                 const int* __restrict__ Vf,
                                                 int* __restrict__ foutf) {
  const int tid = threadIdx.x;
  const int lane = tid & 63;
  const int wid = tid >> 6;
  const int la = lane & 15;
  const int quad = lane >> 4;
  const int b = blockIdx.x & 3;
  const int qbase = (blockIdx.x >> 2) * 16;
  const int* Qb = Qf + (size_t)b * 131072;
  const int* Kb4 = Kf + (size_t)b * 131072;
  const int* Vb4 = Vf + (size_t)b * 131072;

  __shared__ union USm {
    int P16[4][16 * 20];
    struct { float O[4][16][69]; float M[4][16]; float L[4][16]; } e;
  } smu;
  int* myP = smu.P16[wid];

  fragh aq[2];
#pragma unroll
  for (int c = 0; c < 2; ++c)
    *(int4*)aq[c].i4 =
        *(const int4*)&Qb[((c * 256 + (qbase >> 4)) * 64 + quad * 16 + la) * 4];

  f32x4 o[4];
  float mrun = -3.0e38f, lrun = 0.f;
#pragma unroll
  for (int mt = 0; mt < 4; ++mt) o[mt] = f32x4{0.f, 0.f, 0.f, 0.f};

  const int jbeg = wid * (N_ / 4);
  const int jend = jbeg + N_ / 4;

  int4 ka[2][2], kb2[2][2];
#pragma unroll
  for (int nt = 0; nt < 2; ++nt)
#pragma unroll
    for (int g = 0; g < 2; ++g)
      ka[nt][g] = *(const int4*)&Kb4[((g * 256 + (jbeg >> 4) + nt) * 64 + lane) * 4];

  auto body = [&](int j0, int4 (&kc)[2][2], int4 (&kn)[2][2]) {
    f32x4 s[2];
#pragma unroll
    for (int nt = 0; nt < 2; ++nt) {
      fragh k0, k1;
      k0.i4[0] = kc[nt][0].x; k0.i4[1] = kc[nt][0].y;
      k0.i4[2] = kc[nt][0].z; k0.i4[3] = kc[nt][0].w;
      k1.i4[0] = kc[nt][1].x; k1.i4[1] = kc[nt][1].y;
      k1.i4[2] = kc[nt][1].z; k1.i4[3] = kc[nt][1].w;
      f32x4 z = f32x4{0.f, 0.f, 0.f, 0.f};
      z = __builtin_amdgcn_mfma_f32_16x16x32_f16(k0.h8, aq[0].h8, z, 0, 0, 0);
      s[nt] = __builtin_amdgcn_mfma_f32_16x16x32_f16(k1.h8, aq[1].h8, z, 0, 0, 0);
    }
    int4 vv[4];
#pragma unroll
    for (int mt = 0; mt < 4; ++mt)
      vv[mt] = *(const int4*)&Vb4[(((j0 >> 5) * 4 + mt) * 64 + lane) * 4];
    const int nj = (j0 + 32 < jend) ? (j0 + 32) : jbeg;
#pragma unroll
    for (int nt = 0; nt < 2; ++nt)
#pragma unroll
      for (int g = 0; g < 2; ++g)
        kn[nt][g] = *(const int4*)&Kb4[((g * 256 + (nj >> 4) + nt) * 64 + lane) * 4];
    float t0 = fmaxf(fmaxf(s[0][0], s[0][1]), fmaxf(s[0][2], s[0][3]));
    float t1 = fmaxf(fmaxf(s[1][0], s[1][1]), fmaxf(s[1][2], s[1][3]));
    float t = fmaxf(t0, t1);
    t = fmaxf(t, __shfl_xor(t, 16));
    t = fmaxf(t, __shfl_xor(t, 32));
    float mnew = fmaxf(mrun, t);
    float alpha = __expf(mrun - mnew);
    float p[2][4];
    float ps = 0.f;
#pragma unroll
    for (int nt = 0; nt < 2; ++nt)
#pragma unroll
      for (int r = 0; r < 4; ++r) {
        p[nt][r] = __expf(s[nt][r] - mnew);
        ps += p[nt][r];
      }
    ps += __shfl_xor(ps, 16);
    ps += __shfl_xor(ps, 32);
    lrun = lrun * alpha + ps;
    mrun = mnew;
#pragma unroll
    for (int nt = 0; nt < 2; ++nt) {
      myP[(nt * 8 + quad * 2 + 0) * 20 + la] = pkh(p[nt][0], p[nt][1]);
      myP[(nt * 8 + quad * 2 + 1) * 20 + la] = pkh(p[nt][2], p[nt][3]);
    }
    __asm__ __volatile__("s_waitcnt lgkmcnt(0)" ::: "memory");
    fragh pb;
#pragma unroll
    for (int j = 0; j < 4; ++j) pb.i4[j] = myP[(quad * 4 + j) * 20 + la];
#pragma unroll
    for (int mt = 0; mt < 4; ++mt) {
      o[mt][0] *= alpha; o[mt][1] *= alpha;
      o[mt][2] *= alpha; o[mt][3] *= alpha;
    }
#pragma unroll
    for (int mt = 0; mt < 4; ++mt) {
      fragh vb;
      vb.i4[0] = vv[mt].x; vb.i4[1] = vv[mt].y;
      vb.i4[2] = vv[mt].z; vb.i4[3] = vv[mt].w;
      o[mt] = __builtin_amdgcn_mfma_f32_16x16x32_f16(vb.h8, pb.h8, o[mt], 0, 0, 0);
    }
  };

#pragma unroll 1
  for (int j0 = jbeg; j0 < jend; j0 += 64) {
    body(j0, ka, kb2);
    body(j0 + 32, kb2, ka);
  }

  __syncthreads();
  if (quad == 0) {
    smu.e.M[wid][la] = mrun;
    smu.e.L[wid][la] = lrun;
  }
#pragma unroll
  for (int mt = 0; mt < 4; ++mt)
#pragma unroll
    for (int r = 0; r < 4; ++r) smu.e.O[wid][la][mt * 16 + quad * 4 + r] = o[mt][r];
  __syncthreads();

  // epilogue: combine partials and emit fout directly as convup B-frags (m-pairs)
#pragma unroll
  for (int t = 0; t < 2; ++t) {
    int pidx = t * 256 + tid;
    int p = pidx >> 4;   // pair index = m>>1, 0..31
    int q = pidx & 15;
    float m0 = fmaxf(fmaxf(smu.e.M[0][q], smu.e.M[1][q]),
                     fmaxf(smu.e.M[2][q], smu.e.M[3][q]));
    float num0 = 0.f, num1 = 0.f, den = 0.f;
#pragma unroll
    for (int w = 0; w < 4; ++w) {
      float wgt = __expf(smu.e.M[w][q] - m0);
      num0 += wgt * smu.e.O[w][q][2 * p];
      num1 += wgt * smu.e.O[w][q][2 * p + 1];
      den += wgt * smu.e.L[w][q];
    }
    float inv = 1.f / den;
    int h, l;
    pk_hl(num0 * inv, num1 * inv, h, l);
    int kt = p >> 4, qz = (p >> 2) & 3, jj = p & 3;
    int addr = (((b * 2 + kt) * 256 + (qbase >> 4)) * 64 + qz * 16 + q) * 4 + jj;
    foutf[addr] = h;
    foutf[524288 + addr] = l;
  }
}

// ---------------- f_up conv: split-fp16 MFMA (K=64 over m, O=512) ------------------
// 2 ntg/wave, grid (128, 8) = 1024 blocks = 4/CU. Straight-line prefetch (KT=2).
__global__ __launch_bounds__(256) void convup_k(const int* __restrict__ foutf,
                                                const int* __restrict__ wuf,
                                                float* __restrict__ u,
                                                float* __restrict__ stats) {
  const int t = threadIdx.x;
  const int lane = t & 63;
  const int wv = t >> 6;
  const int la = lane & 15;
  const int quad = lane >> 4;
  const int b = blockIdx.x >> 5;
  const int ns = blockIdx.x & 31;
  const int o0g = blockIdx.y * 4;  // otg base (4 otg = 64 o per block)
  const int ntg0 = ns * 8 + wv * 2;

  f32x4 acc[4][2];
#pragma unroll
  for (int ot = 0; ot < 4; ++ot)
#pragma unroll
    for (int nt = 0; nt < 2; ++nt) acc[ot][nt] = f32x4{0.f, 0.f, 0.f, 0.f};

  auto loadF = [&](int kt, fragh (&wh)[4], fragh (&wl)[4], fragh (&ah)[2],
                   fragh (&al)[2]) {
#pragma unroll
    for (int ot = 0; ot < 4; ++ot) {
      const int base = (((o0g + ot) * 2 + kt) * 64 + lane) * 4;
      *(int4*)wh[ot].i4 = *(const int4*)&wuf[base];
      *(int4*)wl[ot].i4 = *(const int4*)&wuf[16384 + base];
    }
#pragma unroll
    for (int nt = 0; nt < 2; ++nt) {
      const int abase = (((b * 2 + kt) * 256 + ntg0 + nt) * 64 + lane) * 4;
      *(int4*)ah[nt].i4 = *(const int4*)&foutf[abase];
      *(int4*)al[nt].i4 = *(const int4*)&foutf[524288 + abase];
    }
  };
  auto mm = [&](fragh (&wh)[4], fragh (&wl)[4], fragh (&ah)[2], fragh (&al)[2]) {
#pragma unroll
    for (int ot = 0; ot < 4; ++ot)
#pragma unroll
      for (int nt = 0; nt < 2; ++nt) {
        acc[ot][nt] = __builtin_amdgcn_mfma_f32_16x16x32_f16(wh[ot].h8, ah[nt].h8, acc[ot][nt], 0, 0, 0);
        acc[ot][nt] = __builtin_amdgcn_mfma_f32_16x16x32_f16(wh[ot].h8, al[nt].h8, acc[ot][nt], 0, 0, 0);
        acc[ot][nt] = __builtin_amdgcn_mfma_f32_16x16x32_f16(wl[ot].h8, ah[nt].h8, acc[ot][nt], 0, 0, 0);
      }
  };

  fragh whA[4], wlA[4], ahA[2], alA[2];
  fragh whB[4], wlB[4], ahB[2], alB[2];
  loadF(0, whA, wlA, ahA, alA);
  loadF(1, whB, wlB, ahB, alB);
  mm(whA, wlA, ahA, alA);
  mm(whB, wlB, ahB, alB);

  // u planar fp32 write: o = (o0g+ot)*16 + quad*4 + r, n = (ntg0+nt)*16 + la
#pragma unroll
  for (int ot = 0; ot < 4; ++ot)
#pragma unroll
    for (int nt = 0; nt < 2; ++nt) {
#pragma unroll
      for (int r = 0; r < 4; ++r) {
        const int o = (o0g + ot) * 16 + quad * 4 + r;
        u[((size_t)b * 512 + o) * N_ + (ntg0 + nt) * 16 + la] = acc[ot][nt][r];
      }
    }
#pragma unroll
  for (int ot = 0; ot < 4; ++ot)
#pragma unroll
    for (int r = 0; r < 4; ++r) {
      float s = acc[ot][0][r] + acc[ot][1][r];
      float q = acc[ot][0][r] * acc[ot][0][r] + acc[ot][1][r] * acc[ot][1][r];
#pragma unroll
      for (int d = 1; d < 16; d <<= 1) { s += __shfl_xor(s, d); q += __shfl_xor(q, d); }
      if (la == 0) {
        const int o = (o0g + ot) * 16 + quad * 4 + r;
        atomicAdd(&stats[768 + o], s);
        atomicAdd(&stats[1280 + o], q);
      }
    }
}

// ---------------- residual + final BN ----------------------------------------------
__global__ __launch_bounds__(256) void final_k(const float* __restrict__ x,
                                               const float* __restrict__ u,
                                               const float* __restrict__ gu,
                                               const float* __restrict__ bu,
                                               const float* __restrict__ stats,
                                               float* __restrict__ out) {
  size_t idx = (size_t)blockIdx.x * 256 + threadIdx.x;
  int c = (int)((idx >> 12) & 511);
  float mean = stats[768 + c] * (1.f / CNT);
  float var = stats[1280 + c] * (1.f / CNT) - mean * mean;
  float r = rsqrtf(var + 1e-5f);
  float s = gu[c] * r;
  float sh = bu[c] - mean * s;
  out[idx] = x[idx] + u[idx] * s + sh;
}

extern "C" void kernel_launch(void* const* d_in, const int* in_sizes, int n_in,
                              void* d_out, int out_size, void* d_ws, size_t ws_size,
                              hipStream_t stream) {
  const float* x = (const float*)d_in[0];
  const float* y = (const float*)d_in[1];
  const float* ws1 = (const float*)d_in[2];
  const float* gs1 = (const float*)d_in[3];
  const float* bs1 = (const float*)d_in[4];
  const float* ws2 = (const float*)d_in[5];
  const float* gs2 = (const float*)d_in[6];
  const float* bs2 = (const float*)d_in[7];
  const float* wx1 = (const float*)d_in[8];
  const float* gx1 = (const float*)d_in[9];
  const float* bx1 = (const float*)d_in[10];
  const float* wx2 = (const float*)d_in[11];
  const float* gx2 = (const float*)d_in[12];
  const float* bx2 = (const float*)d_in[13];
  const float* wy1 = (const float*)d_in[14];
  const float* gy1 = (const float*)d_in[15];
  const float* by1 = (const float*)d_in[16];
  const float* wy2 = (const float*)d_in[17];
  const float* gy2 = (const float*)d_in[18];
  const float* by2 = (const float*)d_in[19];
  const float* wu = (const float*)d_in[20];
  const float* gu = (const float*)d_in[21];
  const float* bu = (const float*)d_in[22];
  float* out = (float*)d_out;

  float* w = (float*)d_ws;
  const size_t M1 = 1048576;
  int* z1f = (int*)w;                      // 3M ints: [branch][hi .5M | lo .5M]
  int* z2f = (int*)(w + 3 * M1);           // 3M ints
  int* foutf = (int*)(w + 6 * M1);         // 1M ints (hi .5M | lo .5M)
  float* u = w + 7 * M1;                   // 8M fp32
  int* Afx = (int*)u;                      // 8M ints (hi 4M | lo 4M); dead pre-convup
  int* Afy = (int*)(w + 3 * M1);           // 4M ints over z2f+foutf; dead pre-conv2
  int* Qf = (int*)(w + 15 * M1);
  int* Kf = Qf + 524288;
  int* Vf = Kf + 524288;
  float* stats = (float*)(Vf + 524288);    // 1792 floats
  int* wt1f = (int*)(stats + 1792);        // 81920 ints
  int* wt2f = wt1f + 81920;                // 12288 ints
  float* biasf = (float*)(wt2f + 12288);   // 192 floats
  int* wuf = (int*)(biasf + 192);          // 32768 ints

  hipMemsetAsync(stats, 0, 1792 * sizeof(float), stream);

  prep1_k<<<dim3(160), dim3(256), 0, stream>>>(ws1, wx1, wy1, wt1f);
  packA_k<<<dim3(4096, 2), dim3(256), 0, stream>>>(x, y, Afx, Afy);
  conv1_k<<<dim3(256, 3), dim3(256), 0, stream>>>(Afx, Afy, wt1f, z1f, stats);
  prep2_k<<<dim3(3), dim3(256), 0, stream>>>(ws2, wx2, wy2, gs1, bs1, gx1, bx1,
                                             gy1, by1, stats, wt2f, biasf);
  conv2_k<<<dim3(256, 3), dim3(256), 0, stream>>>(z1f, wt2f, biasf, z2f, stats);
  prepu_k<<<dim3(64), dim3(256), 0, stream>>>(wu, wuf);
  pack_k<<<dim3(2048, 1, 3), dim3(256), 0, stream>>>(z2f, gs2, bs2, gx2, bx2, gy2,
                                                     by2, Qf, Kf, Vf, stats);
  attn_k<<<dim3(1024), dim3(256), 0, stream>>>(Qf, Kf, Vf, foutf);
  convup_k<<<dim3(128, 8), dim3(256), 0, stream>>>(foutf, wuf, u, stats);
  final_k<<<dim3(32768), dim3(256), 0, stream>>>(x, u, gu, bu, stats, out);
}

// Round 9
// 367.805 us; speedup vs baseline: 1.8541x; 1.8541x over previous
//
#include <hip/hip_runtime.h>
#include <hip/hip_fp16.h>
#include <cstdint>

// Shapes (hard-coded): B=4, Cx=512, Cy=256, M=64, H=W=64, N=4096
constexpr int N_ = 4096;
constexpr float CNT = 16384.f;  // B*N reduction count for BN stats

typedef __attribute__((ext_vector_type(8))) _Float16 half8;
typedef __attribute__((ext_vector_type(4))) float f32x4;
union fragh { half8 h8; int i4[4]; };

__device__ inline int pkh(float a, float b) {
  union { __half2 h; int i; } u;
  u.h = __float22half2_rn(float2{a, b});
  return u.i;
}
// split-fp16 (Markidis): h = rn(a,b) packed; l = rn(residuals) packed
__device__ inline void pk_hl(float a, float b, int& h, int& l) {
  __half ah = __float2half_rn(a), bh = __float2half_rn(b);
  union { __half2 v; int i; } u;
  u.v = __halves2half2(ah, bh);
  h = u.i;
  float ar = a - __half2float(ah), br = b - __half2float(bh);
  union { __half2 v; int i; } w2;
  w2.v = __float22half2_rn(float2{ar, br});
  l = w2.i;
}
__device__ inline float2 uph(int v) {
  union { __half2 h; int i; } u;
  u.i = v;
  return float2{__half2float(__low2half(u.h)), __half2float(__high2half(u.h))};
}

// Stats layout (floats): group g in {0:s1,1:x1,2:y1,3:s2,4:x2,5:y2}:
//   sum at g*128+c, sumsq at g*128+64+c (c<64). f_up: sum 768+c, sumsq 1280+c.
//
// Fragment layouts (validated r6):
//  B-operand frag buffer (activations): int at
//    ((((bIdx*KT + kt)*256 + ntg)*64 + q*16 + la)*4 + jj)
//    holds fp16 pair (k = kt*32 + q*8 + 2jj, k+1) at col n = ntg*16 + la.
//    hi array then lo array (offset = total hi ints).
//  A-operand frag buffer (weights): int at (((otg*KT + kt)*64 + q*16+la)*4 + jj)
//    holds pair (k...) of W[o = otg*16 + la].
//
// Workspace aliasing (stream-ordered):
//  z1f  w[0..3M)   frag hi/lo per branch (1M ints each: hi .5M | lo .5M)
//  z2f  w[3..6M)   same; Afy aliases w[3..7M) (dead before conv2/attn write)
//  fout w[6..7M)   fp32 planar (attn -> convup)
//  u    w[7..15M)  fp32; Afx aliases it (dead before convup writes)
//  Qf/Kf/Vf at w+15M; stats; wt1f/wt2f/biasf/wut at tail

// ---------------- packA: x,y -> B-fragment hi/lo fp16 ------------------------------
__global__ __launch_bounds__(256) void packA_k(const float* __restrict__ x,
                                               const float* __restrict__ y,
                                               int* __restrict__ Afx,
                                               int* __restrict__ Afy) {
  const int job = blockIdx.y;
  if (job == 1 && blockIdx.x >= 2048) return;
  const int idx = blockIdx.x * 256 + threadIdx.x;
  const float* src = job ? y : x;
  int* dst = job ? Afy : Afx;
  const int KT = job ? 8 : 16;
  const int loOff = job ? 2097152 : 4194304;
  const int n = idx & 4095, q = (idx >> 12) & 3;
  const int kt = job ? ((idx >> 14) & 7) : ((idx >> 14) & 15);
  const int b = job ? (idx >> 17) : (idx >> 18);
  const float* sp = src + ((size_t)(b * (KT * 32) + kt * 32 + q * 8)) * N_ + n;
  float a[8];
#pragma unroll
  for (int j = 0; j < 8; ++j) a[j] = sp[(size_t)j * N_];
  int4 hi, lo;
  pk_hl(a[0], a[1], hi.x, lo.x);
  pk_hl(a[2], a[3], hi.y, lo.y);
  pk_hl(a[4], a[5], hi.z, lo.z);
  pk_hl(a[6], a[7], hi.w, lo.w);
  const int base = (((b * KT + kt) * 256 + (n >> 4)) * 64 + q * 16 + (n & 15)) * 4;
  *(int4*)&dst[base] = hi;
  *(int4*)&dst[loOff + base] = lo;
}

// ---------------- prep1: stage-1 weights -> A-fragment hi/lo -----------------------
__global__ __launch_bounds__(256) void prep1_k(const float* __restrict__ ws1,
                                               const float* __restrict__ wx1,
                                               const float* __restrict__ wy1,
                                               int* __restrict__ wt1f) {
  const int idx = blockIdx.x * 256 + threadIdx.x;  // 0..40959
  const float* W;
  int KT, K, hiBase, loOff, e;
  if (idx < 16384) { W = ws1; KT = 16; K = 512; hiBase = 0; loOff = 16384; e = idx; }
  else if (idx < 32768) { W = wx1; KT = 16; K = 512; hiBase = 32768; loOff = 16384; e = idx - 16384; }
  else { W = wy1; KT = 8; K = 256; hiBase = 65536; loOff = 8192; e = idx - 32768; }
  const int jj = e & 3, lane = (e >> 2) & 63;
  int kt, ot;
  if (KT == 16) { kt = (e >> 8) & 15; ot = e >> 12; } else { kt = (e >> 8) & 7; ot = e >> 11; }
  const int o = ot * 16 + (lane & 15);
  const int k = kt * 32 + (lane >> 4) * 8 + 2 * jj;
  int h, l;
  pk_hl(W[o * K + k], W[o * K + k + 1], h, l);
  wt1f[hiBase + e] = h;
  wt1f[hiBase + loOff + e] = l;
}

// ---------------- prep2: fold BN1 into stage-2 weights -> A-frag hi/lo + bias ------
__global__ __launch_bounds__(256) void prep2_k(
    const float* __restrict__ ws2, const float* __restrict__ wx2,
    const float* __restrict__ wy2,
    const float* __restrict__ gs1, const float* __restrict__ bs1,
    const float* __restrict__ gx1, const float* __restrict__ bx1,
    const float* __restrict__ gy1, const float* __restrict__ by1,
    const float* __restrict__ stats, int* __restrict__ wt2f,
    float* __restrict__ biasf) {
  const int branch = blockIdx.x;
  const int t = threadIdx.x;
  const float* W = branch == 0 ? ws2 : (branch == 1 ? wx2 : wy2);
  const float* g1 = branch == 0 ? gs1 : (branch == 1 ? gx1 : gy1);
  const float* b1 = branch == 0 ? bs1 : (branch == 1 ? bx1 : by1);
  const float* stin = stats + branch * 128;
  int* outW = wt2f + branch * 4096;

  auto scale = [&](int k) {
    float mean = stin[k] * (1.f / CNT);
    float var = stin[64 + k] * (1.f / CNT) - mean * mean;
    return g1[k] * rsqrtf(var + 1e-5f);
  };
#pragma unroll
  for (int i = 0; i < 8; ++i) {
    int e = i * 256 + t;
    int jj = e & 3, lane = (e >> 2) & 63, kt = (e >> 8) & 1, ot = e >> 9;
    int o = ot * 16 + (lane & 15);
    int k = kt * 32 + (lane >> 4) * 8 + 2 * jj;
    float w0 = W[o * 64 + k] * scale(k);
    float w1 = W[o * 64 + k + 1] * scale(k + 1);
    int h, l;
    pk_hl(w0, w1, h, l);
    outW[e] = h;
    outW[2048 + e] = l;
  }
  if (t < 64) {
    float s = 0.f;
    for (int k = 0; k < 64; ++k) {
      float mean = stin[k] * (1.f / CNT);
      float var = stin[64 + k] * (1.f / CNT) - mean * mean;
      float sc = g1[k] * rsqrtf(var + 1e-5f);
      float sh = b1[k] - mean * sc;
      s += W[t * 64 + k] * sh;
    }
    biasf[branch * 64 + t] = s;
  }
}

// ---------------- prep_up: transpose f_up weights to k-major [64][512] -------------
__global__ __launch_bounds__(256) void prepu_k(const float* __restrict__ wu,
                                               float* __restrict__ wut) {
  int e = blockIdx.x * 256 + threadIdx.x;
  int k = e >> 9, o = e & 511;
  wut[e] = wu[o * 64 + k];
}

// ---------------- stage-1 convs: split-fp16 MFMA, 1-wave blocks, branchless --------
// prefetch. Per wave: 4 ntg x 4 ot (48 MFMA : 16 loads per kt, full weight reuse).
// 768 blocks = 3/CU (all CUs busy). Double-buffer with CLAMPED next index (cndmask,
// no branch) so the compiler can keep loads in flight across the MFMA block.
__global__ __launch_bounds__(64) void conv1_k(
    const int* __restrict__ Afx, const int* __restrict__ Afy,
    const int* __restrict__ wt1f, int* __restrict__ z1f,
    float* __restrict__ stats) {
  const int lane = threadIdx.x;
  const int la = lane & 15;
  const int quad = lane >> 4;
  const int b = blockIdx.x >> 6;
  const int ns = blockIdx.x & 63;
  const int branch = blockIdx.y;
  const int KT = branch == 2 ? 8 : 16;
  const int* Af = branch == 2 ? Afy : Afx;
  const int aLo = branch == 2 ? 2097152 : 4194304;
  const int* Wf = wt1f + (branch == 0 ? 0 : (branch == 1 ? 32768 : 65536));
  const int wLo = branch == 2 ? 8192 : 16384;
  float* st = stats + branch * 128;
  int* zb = z1f + branch * 1048576;
  const int ntg0 = ns * 4;

  f32x4 acc[4][4];
#pragma unroll
  for (int i = 0; i < 4; ++i)
#pragma unroll
    for (int j = 0; j < 4; ++j) acc[i][j] = f32x4{0.f, 0.f, 0.f, 0.f};

  auto loadF = [&](int kt, fragh (&wh)[4], fragh (&wl)[4], fragh (&ah)[4],
                   fragh (&al)[4]) {
#pragma unroll
    for (int ot = 0; ot < 4; ++ot) {
      const int base = ((ot * KT + kt) * 64 + lane) * 4;
      *(int4*)wh[ot].i4 = *(const int4*)&Wf[base];
      *(int4*)wl[ot].i4 = *(const int4*)&Wf[wLo + base];
    }
#pragma unroll
    for (int nt = 0; nt < 4; ++nt) {
      const int abase = (((b * KT + kt) * 256 + ntg0 + nt) * 64 + lane) * 4;
      *(int4*)ah[nt].i4 = *(const int4*)&Af[abase];
      *(int4*)al[nt].i4 = *(const int4*)&Af[aLo + abase];
    }
  };
  auto mm = [&](fragh (&wh)[4], fragh (&wl)[4], fragh (&ah)[4], fragh (&al)[4]) {
#pragma unroll
    for (int ot = 0; ot < 4; ++ot)
#pragma unroll
      for (int nt = 0; nt < 4; ++nt) {
        acc[ot][nt] = __builtin_amdgcn_mfma_f32_16x16x32_f16(wh[ot].h8, ah[nt].h8, acc[ot][nt], 0, 0, 0);
        acc[ot][nt] = __builtin_amdgcn_mfma_f32_16x16x32_f16(wh[ot].h8, al[nt].h8, acc[ot][nt], 0, 0, 0);
        acc[ot][nt] = __builtin_amdgcn_mfma_f32_16x16x32_f16(wl[ot].h8, ah[nt].h8, acc[ot][nt], 0, 0, 0);
      }
  };

  fragh whA[4], wlA[4], ahA[4], alA[4];
  fragh whB[4], wlB[4], ahB[4], alB[4];
  loadF(0, whA, wlA, ahA, alA);
#pragma unroll 1
  for (int kt = 0; kt < KT; kt += 2) {
    loadF(kt + 1, whB, wlB, ahB, alB);
    mm(whA, wlA, ahA, alA);
    const int k2 = (kt + 2 < KT) ? kt + 2 : kt;  // clamped: branchless redundant load
    loadF(k2, whA, wlA, ahA, alA);
    mm(whB, wlB, ahB, alB);
  }

  // z1 frag write: o = ot*16+quad*4+r, pairs (r0,r1),(r2,r3) are in-lane
#pragma unroll
  for (int ot = 0; ot < 4; ++ot) {
    const int ktz = ot >> 1;
    const int qz = (ot & 1) * 2 + (quad >> 1);
    const int jz = (quad & 1) * 2;
#pragma unroll
    for (int nt = 0; nt < 4; ++nt) {
      const int addr = (((b * 2 + ktz) * 256 + ntg0 + nt) * 64 + qz * 16 + la) * 4 + jz;
      int h0, l0, h1, l1;
      pk_hl(acc[ot][nt][0], acc[ot][nt][1], h0, l0);
      pk_hl(acc[ot][nt][2], acc[ot][nt][3], h1, l1);
      *(int2*)&zb[addr] = int2{h0, h1};
      *(int2*)&zb[524288 + addr] = int2{l0, l1};
    }
  }
#pragma unroll
  for (int ot = 0; ot < 4; ++ot)
#pragma unroll
    for (int r = 0; r < 4; ++r) {
      float s = acc[ot][0][r] + acc[ot][1][r] + acc[ot][2][r] + acc[ot][3][r];
      float q = acc[ot][0][r] * acc[ot][0][r] + acc[ot][1][r] * acc[ot][1][r] +
                acc[ot][2][r] * acc[ot][2][r] + acc[ot][3][r] * acc[ot][3][r];
#pragma unroll
      for (int d = 1; d < 16; d <<= 1) { s += __shfl_xor(s, d); q += __shfl_xor(q, d); }
      if (la == 0) {
        atomicAdd(&st[ot * 16 + quad * 4 + r], s);
        atomicAdd(&st[64 + ot * 16 + quad * 4 + r], q);
      }
    }
}

// ---------------- stage-2 convs: split-fp16 MFMA, 1-wave blocks, straight-line -----
__global__ __launch_bounds__(64) void conv2_k(
    const int* __restrict__ z1f, const int* __restrict__ wt2f,
    const float* __restrict__ biasf, int* __restrict__ z2f,
    float* __restrict__ stats) {
  const int lane = threadIdx.x;
  const int la = lane & 15;
  const int quad = lane >> 4;
  const int b = blockIdx.x >> 6;
  const int ns = blockIdx.x & 63;
  const int branch = blockIdx.y;
  const int* Af = z1f + branch * 1048576;
  const int* Wf = wt2f + branch * 4096;
  const float* bias = biasf + branch * 64;
  float* st = stats + (3 + branch) * 128;
  int* zb = z2f + branch * 1048576;
  const int ntg0 = ns * 4;

  f32x4 acc[4][4];
#pragma unroll
  for (int ot = 0; ot < 4; ++ot)
#pragma unroll
    for (int nt = 0; nt < 4; ++nt) {
#pragma unroll
      for (int r = 0; r < 4; ++r) acc[ot][nt][r] = bias[ot * 16 + quad * 4 + r];
    }

  auto loadF = [&](int kt, fragh (&wh)[4], fragh (&wl)[4], fragh (&ah)[4],
                   fragh (&al)[4]) {
#pragma unroll
    for (int ot = 0; ot < 4; ++ot) {
      const int base = ((ot * 2 + kt) * 64 + lane) * 4;
      *(int4*)wh[ot].i4 = *(const int4*)&Wf[base];
      *(int4*)wl[ot].i4 = *(const int4*)&Wf[2048 + base];
    }
#pragma unroll
    for (int nt = 0; nt < 4; ++nt) {
      const int abase = (((b * 2 + kt) * 256 + ntg0 + nt) * 64 + lane) * 4;
      *(int4*)ah[nt].i4 = *(const int4*)&Af[abase];
      *(int4*)al[nt].i4 = *(const int4*)&Af[524288 + abase];
    }
  };
  auto mm = [&](fragh (&wh)[4], fragh (&wl)[4], fragh (&ah)[4], fragh (&al)[4]) {
#pragma unroll
    for (int ot = 0; ot < 4; ++ot)
#pragma unroll
      for (int nt = 0; nt < 4; ++nt) {
        acc[ot][nt] = __builtin_amdgcn_mfma_f32_16x16x32_f16(wh[ot].h8, ah[nt].h8, acc[ot][nt], 0, 0, 0);
        acc[ot][nt] = __builtin_amdgcn_mfma_f32_16x16x32_f16(wh[ot].h8, al[nt].h8, acc[ot][nt], 0, 0, 0);
        acc[ot][nt] = __builtin_amdgcn_mfma_f32_16x16x32_f16(wl[ot].h8, ah[nt].h8, acc[ot][nt], 0, 0, 0);
      }
  };

  fragh whA[4], wlA[4], ahA[4], alA[4];
  fragh whB[4], wlB[4], ahB[4], alB[4];
  loadF(0, whA, wlA, ahA, alA);
  loadF(1, whB, wlB, ahB, alB);
  mm(whA, wlA, ahA, alA);
  mm(whB, wlB, ahB, alB);

#pragma unroll
  for (int ot = 0; ot < 4; ++ot) {
    const int ktz = ot >> 1;
    const int qz = (ot & 1) * 2 + (quad >> 1);
    const int jz = (quad & 1) * 2;
#pragma unroll
    for (int nt = 0; nt < 4; ++nt) {
      const int addr = (((b * 2 + ktz) * 256 + ntg0 + nt) * 64 + qz * 16 + la) * 4 + jz;
      int h0, l0, h1, l1;
      pk_hl(acc[ot][nt][0], acc[ot][nt][1], h0, l0);
      pk_hl(acc[ot][nt][2], acc[ot][nt][3], h1, l1);
      *(int2*)&zb[addr] = int2{h0, h1};
      *(int2*)&zb[524288 + addr] = int2{l0, l1};
    }
  }
#pragma unroll
  for (int ot = 0; ot < 4; ++ot)
#pragma unroll
    for (int r = 0; r < 4; ++r) {
      float s = acc[ot][0][r] + acc[ot][1][r] + acc[ot][2][r] + acc[ot][3][r];
      float q = acc[ot][0][r] * acc[ot][0][r] + acc[ot][1][r] * acc[ot][1][r] +
                acc[ot][2][r] * acc[ot][2][r] + acc[ot][3][r] * acc[ot][3][r];
#pragma unroll
      for (int d = 1; d < 16; d <<= 1) { s += __shfl_xor(s, d); q += __shfl_xor(q, d); }
      if (la == 0) {
        atomicAdd(&st[ot * 16 + quad * 4 + r], s);
        atomicAdd(&st[64 + ot * 16 + quad * 4 + r], q);
      }
    }
}

// ---------------- pack Q/K/V from frag-format z2 with inline BN2 -------------------
__global__ __launch_bounds__(256) void pack_k(
    const int* __restrict__ z2f,
    const float* __restrict__ gs2, const float* __restrict__ bs2,
    const float* __restrict__ gx2, const float* __restrict__ bx2,
    const float* __restrict__ gy2, const float* __restrict__ by2,
    int* __restrict__ Qf, int* __restrict__ Kf, int* __restrict__ Vf,
    const float* __restrict__ stats) {
  const int job = blockIdx.z;  // 0: Q<-x2, 1: K<-y2, 2: V<-s2
  const int idx = blockIdx.x * 256 + threadIdx.x;
  const float* g2 = job == 0 ? gx2 : (job == 1 ? gy2 : gs2);
  const float* b2 = job == 0 ? bx2 : (job == 1 ? by2 : bs2);
  const float* st = stats + (job == 0 ? 4 : (job == 1 ? 5 : 3)) * 128;

  auto snorm = [&](int c, float& s, float& h) {
    float mean = st[c] * (1.f / CNT);
    float var = st[64 + c] * (1.f / CNT) - mean * mean;
    float r = rsqrtf(var + 1e-5f);
    s = g2[c] * r;
    h = b2[c] - mean * s;
  };
  if (job < 2) {
    const int* zf = z2f + (job == 0 ? 1048576 : 2097152);
    int* outp = job == 0 ? Qf : Kf;
    int h = zf[idx], l = zf[524288 + idx];
    int jj = idx & 3, lane = (idx >> 2) & 63, q = lane >> 4;
    int kt = (idx >> 16) & 1;
    int c0 = 2 * (kt * 16 + q * 4 + jj);
    float s0, h0, s1, h1;
    snorm(c0, s0, h0);
    snorm(c0 + 1, s1, h1);
    float2 vh = uph(h), vl = uph(l);
    outp[idx] = pkh((vh.x + vl.x) * s0 + h0, (vh.y + vl.y) * s1 + h1);
  } else {
    int w_ = idx & 3, lane = (idx >> 2) & 63, la_v = lane & 15, q_v = lane >> 4;
    int mt = (idx >> 8) & 3, kb = (idx >> 10) & 127, b = idx >> 17;
    int ch = mt * 16 + la_v;
    int k = kb * 16 + q_v * 4 + w_;
    int n0 = 2 * k;
    int kp = ch >> 1, kt = kp >> 4, qz = (kp >> 2) & 3, jz = kp & 3, half = ch & 1;
    int a0 = (((b * 2 + kt) * 256 + (n0 >> 4)) * 64 + qz * 16 + (n0 & 15)) * 4 + jz;
    float2 h0v = uph(z2f[a0]), l0v = uph(z2f[524288 + a0]);
    float2 h1v = uph(z2f[a0 + 4]), l1v = uph(z2f[524288 + a0 + 4]);
    float v0 = half ? (h0v.y + l0v.y) : (h0v.x + l0v.x);
    float v1 = half ? (h1v.y + l1v.y) : (h1v.x + l1v.x);
    float s0, h0;
    snorm(ch, s0, h0);
    Vf[idx] = pkh(v0 * s0 + h0, v1 * s0 + h0);
  }
}

// ---------------- MFMA fp16 flash attention (r6 version, planar fout) --------------
__global__ __launch_bounds__(256, 4) void attn_k(const int* __restrict__ Qf,
                                                 const int* __restrict__ Kf,
                                                 const int* __restrict__ Vf,
                                                 float* __restrict__ fout) {
  const int tid = threadIdx.x;
  const int lane = tid & 63;
  const int wid = tid >> 6;
  const int la = lane & 15;
  const int quad = lane >> 4;
  const int b = blockIdx.x & 3;
  const int qbase = (blockIdx.x >> 2) * 16;
  const int* Qb = Qf + (size_t)b * 131072;
  const int* Kb4 = Kf + (size_t)b * 131072;
  const int* Vb4 = Vf + (size_t)b * 131072;

  __shared__ union USm {
    int P16[4][16 * 20];
    struct { float O[4][16][69]; float M[4][16]; float L[4][16]; } e;
  } smu;
  int* myP = smu.P16[wid];

  fragh aq[2];
#pragma unroll
  for (int c = 0; c < 2; ++c)
    *(int4*)aq[c].i4 =
        *(const int4*)&Qb[((c * 256 + (qbase >> 4)) * 64 + quad * 16 + la) * 4];

  f32x4 o[4];
  float mrun = -3.0e38f, lrun = 0.f;
#pragma unroll
  for (int mt = 0; mt < 4; ++mt) o[mt] = f32x4{0.f, 0.f, 0.f, 0.f};

  const int jbeg = wid * (N_ / 4);
  const int jend = jbeg + N_ / 4;

  int4 ka[2][2], kb2[2][2];
#pragma unroll
  for (int nt = 0; nt < 2; ++nt)
#pragma unroll
    for (int g = 0; g < 2; ++g)
      ka[nt][g] = *(const int4*)&Kb4[((g * 256 + (jbeg >> 4) + nt) * 64 + lane) * 4];

  auto body = [&](int j0, int4 (&kc)[2][2], int4 (&kn)[2][2]) {
    f32x4 s[2];
#pragma unroll
    for (int nt = 0; nt < 2; ++nt) {
      fragh k0, k1;
      k0.i4[0] = kc[nt][0].x; k0.i4[1] = kc[nt][0].y;
      k0.i4[2] = kc[nt][0].z; k0.i4[3] = kc[nt][0].w;
      k1.i4[0] = kc[nt][1].x; k1.i4[1] = kc[nt][1].y;
      k1.i4[2] = kc[nt][1].z; k1.i4[3] = kc[nt][1].w;
      f32x4 z = f32x4{0.f, 0.f, 0.f, 0.f};
      z = __builtin_amdgcn_mfma_f32_16x16x32_f16(k0.h8, aq[0].h8, z, 0, 0, 0);
      s[nt] = __builtin_amdgcn_mfma_f32_16x16x32_f16(k1.h8, aq[1].h8, z, 0, 0, 0);
    }
    int4 vv[4];
#pragma unroll
    for (int mt = 0; mt < 4; ++mt)
      vv[mt] = *(const int4*)&Vb4[(((j0 >> 5) * 4 + mt) * 64 + lane) * 4];
    const int nj = (j0 + 32 < jend) ? (j0 + 32) : jbeg;
#pragma unroll
    for (int nt = 0; nt < 2; ++nt)
#pragma unroll
      for (int g = 0; g < 2; ++g)
        kn[nt][g] = *(const int4*)&Kb4[((g * 256 + (nj >> 4) + nt) * 64 + lane) * 4];
    float t0 = fmaxf(fmaxf(s[0][0], s[0][1]), fmaxf(s[0][2], s[0][3]));
    float t1 = fmaxf(fmaxf(s[1][0], s[1][1]), fmaxf(s[1][2], s[1][3]));
    float t = fmaxf(t0, t1);
    t = fmaxf(t, __shfl_xor(t, 16));
    t = fmaxf(t, __shfl_xor(t, 32));
    float mnew = fmaxf(mrun, t);
    float alpha = __expf(mrun - mnew);
    float p[2][4];
    float ps = 0.f;
#pragma unroll
    for (int nt = 0; nt < 2; ++nt)
#pragma unroll
      for (int r = 0; r < 4; ++r) {
        p[nt][r] = __expf(s[nt][r] - mnew);
        ps += p[nt][r];
      }
    ps += __shfl_xor(ps, 16);
    ps += __shfl_xor(ps, 32);
    lrun = lrun * alpha + ps;
    mrun = mnew;
#pragma unroll
    for (int nt = 0; nt < 2; ++nt) {
      myP[(nt * 8 + quad * 2 + 0) * 20 + la] = pkh(p[nt][0], p[nt][1]);
      myP[(nt * 8 + quad * 2 + 1) * 20 + la] = pkh(p[nt][2], p[nt][3]);
    }
    __asm__ __volatile__("s_waitcnt lgkmcnt(0)" ::: "memory");
    fragh pb;
#pragma unroll
    for (int j = 0; j < 4; ++j) pb.i4[j] = myP[(quad * 4 + j) * 20 + la];
#pragma unroll
    for (int mt = 0; mt < 4; ++mt) {
      o[mt][0] *= alpha; o[mt][1] *= alpha;
      o[mt][2] *= alpha; o[mt][3] *= alpha;
    }
#pragma unroll
    for (int mt = 0; mt < 4; ++mt) {
      fragh vb;
      vb.i4[0] = vv[mt].x; vb.i4[1] = vv[mt].y;
      vb.i4[2] = vv[mt].z; vb.i4[3] = vv[mt].w;
      o[mt] = __builtin_amdgcn_mfma_f32_16x16x32_f16(vb.h8, pb.h8, o[mt], 0, 0, 0);
    }
  };

#pragma unroll 1
  for (int j0 = jbeg; j0 < jend; j0 += 64) {
    body(j0, ka, kb2);
    body(j0 + 32, kb2, ka);
  }

  __syncthreads();
  if (quad == 0) {
    smu.e.M[wid][la] = mrun;
    smu.e.L[wid][la] = lrun;
  }
#pragma unroll
  for (int mt = 0; mt < 4; ++mt)
#pragma unroll
    for (int r = 0; r < 4; ++r) smu.e.O[wid][la][mt * 16 + quad * 4 + r] = o[mt][r];
  __syncthreads();

#pragma unroll
  for (int t = 0; t < 4; ++t) {
    int oidx = t * 256 + tid;
    int m = oidx >> 4;
    int q = oidx & 15;
    float m0 = fmaxf(fmaxf(smu.e.M[0][q], smu.e.M[1][q]),
                     fmaxf(smu.e.M[2][q], smu.e.M[3][q]));
    float num = 0.f, den = 0.f;
#pragma unroll
    for (int w = 0; w < 4; ++w) {
      float wgt = __expf(smu.e.M[w][q] - m0);
      num += wgt * smu.e.O[w][q][m];
      den += wgt * smu.e.L[w][q];
    }
    fout[((size_t)b * 64 + m) * N_ + qbase + q] = num / den;
  }
}

// ---------------- f_up conv (K=64, O=512): FP32 SGEMM (r6 version) -----------------
__global__ __launch_bounds__(256) void convup_k(const float* __restrict__ fout,
                                                const float* __restrict__ wut,
                                                float* __restrict__ u,
                                                float* __restrict__ stats) {
  const int t = threadIdx.x;
  const int b = blockIdx.x >> 4;
  const int n0 = (blockIdx.x & 15) * 256;
  const int o0 = blockIdx.y * 64;

  __shared__ float sA[16][260];
  __shared__ float sW[16][68];

  const int ng4 = (t & 31) * 4;
  const int og8 = (t >> 5) * 8;
  float acc[8][8];
#pragma unroll
  for (int i = 0; i < 8; ++i)
#pragma unroll
    for (int j = 0; j < 8; ++j) acc[i][j] = 0.f;

  const float* Ap = fout + ((size_t)b * 64 + (t >> 6)) * N_ + n0 + (t & 63) * 4;
  const float* Wp = wut + (size_t)(t >> 4) * 512 + o0 + (t & 15) * 4;
  const int arow = t >> 6, acol = (t & 63) * 4;
  const int wrow = t >> 4, wcol = (t & 15) * 4;

  float4 pa[4];
  float4 pw;
#pragma unroll
  for (int i = 0; i < 4; ++i) pa[i] = *(const float4*)(Ap + (size_t)(4 * i) * N_);
  pw = *(const float4*)Wp;
  Ap += (size_t)16 * N_;
  Wp += 16 * 512;
#pragma unroll
  for (int i = 0; i < 4; ++i) *(float4*)&sA[arow + 4 * i][acol] = pa[i];
  *(float4*)&sW[wrow][wcol] = pw;
  __syncthreads();

#pragma unroll 1
  for (int k0 = 0; k0 < 64; k0 += 16) {
    const bool more = (k0 + 16) < 64;
    if (more) {
#pragma unroll
      for (int i = 0; i < 4; ++i) pa[i] = *(const float4*)(Ap + (size_t)(4 * i) * N_);
      pw = *(const float4*)Wp;
      Ap += (size_t)16 * N_;
      Wp += 16 * 512;
    }
#pragma unroll
    for (int k = 0; k < 16; ++k) {
      float4 a0 = *(const float4*)&sA[k][ng4];
      float4 a1 = *(const float4*)&sA[k][128 + ng4];
      float4 w0 = *(const float4*)&sW[k][og8];
      float4 w1 = *(const float4*)&sW[k][og8 + 4];
      float av[8] = {a0.x, a0.y, a0.z, a0.w, a1.x, a1.y, a1.z, a1.w};
      float wv[8] = {w0.x, w0.y, w0.z, w0.w, w1.x, w1.y, w1.z, w1.w};
#pragma unroll
      for (int i = 0; i < 8; ++i)
#pragma unroll
        for (int j = 0; j < 8; ++j) acc[i][j] = fmaf(wv[i], av[j], acc[i][j]);
    }
    __syncthreads();
    if (more) {
#pragma unroll
      for (int i = 0; i < 4; ++i) *(float4*)&sA[arow + 4 * i][acol] = pa[i];
      *(float4*)&sW[wrow][wcol] = pw;
    }
    __syncthreads();
  }

  float* Cb = u + ((size_t)b * 512 + o0 + og8) * N_ + n0;
#pragma unroll
  for (int i = 0; i < 8; ++i) {
    float4 v0 = {acc[i][0], acc[i][1], acc[i][2], acc[i][3]};
    float4 v1 = {acc[i][4], acc[i][5], acc[i][6], acc[i][7]};
    *(float4*)&Cb[(size_t)i * N_ + ng4] = v0;
    *(float4*)&Cb[(size_t)i * N_ + 128 + ng4] = v1;
  }
#pragma unroll
  for (int i = 0; i < 8; ++i) {
    float s = 0.f, q = 0.f;
#pragma unroll
    for (int j = 0; j < 8; ++j) { s += acc[i][j]; q += acc[i][j] * acc[i][j]; }
#pragma unroll
    for (int d = 1; d < 32; d <<= 1) { s += __shfl_xor(s, d); q += __shfl_xor(q, d); }
    if ((t & 31) == 0) {
      atomicAdd(&stats[768 + o0 + og8 + i], s);
      atomicAdd(&stats[1280 + o0 + og8 + i], q);
    }
  }
}

// ---------------- residual + final BN ----------------------------------------------
__global__ __launch_bounds__(256) void final_k(const float* __restrict__ x,
                                               const float* __restrict__ u,
                                               const float* __restrict__ gu,
                                               const float* __restrict__ bu,
                                               const float* __restrict__ stats,
                                               float* __restrict__ out) {
  size_t idx = (size_t)blockIdx.x * 256 + threadIdx.x;
  int c = (int)((idx >> 12) & 511);
  float mean = stats[768 + c] * (1.f / CNT);
  float var = stats[1280 + c] * (1.f / CNT) - mean * mean;
  float r = rsqrtf(var + 1e-5f);
  float s = gu[c] * r;
  float sh = bu[c] - mean * s;
  out[idx] = x[idx] + u[idx] * s + sh;
}

extern "C" void kernel_launch(void* const* d_in, const int* in_sizes, int n_in,
                              void* d_out, int out_size, void* d_ws, size_t ws_size,
                              hipStream_t stream) {
  const float* x = (const float*)d_in[0];
  const float* y = (const float*)d_in[1];
  const float* ws1 = (const float*)d_in[2];
  const float* gs1 = (const float*)d_in[3];
  const float* bs1 = (const float*)d_in[4];
  const float* ws2 = (const float*)d_in[5];
  const float* gs2 = (const float*)d_in[6];
  const float* bs2 = (const float*)d_in[7];
  const float* wx1 = (const float*)d_in[8];
  const float* gx1 = (const float*)d_in[9];
  const float* bx1 = (const float*)d_in[10];
  const float* wx2 = (const float*)d_in[11];
  const float* gx2 = (const float*)d_in[12];
  const float* bx2 = (const float*)d_in[13];
  const float* wy1 = (const float*)d_in[14];
  const float* gy1 = (const float*)d_in[15];
  const float* by1 = (const float*)d_in[16];
  const float* wy2 = (const float*)d_in[17];
  const float* gy2 = (const float*)d_in[18];
  const float* by2 = (const float*)d_in[19];
  const float* wu = (const float*)d_in[20];
  const float* gu = (const float*)d_in[21];
  const float* bu = (const float*)d_in[22];
  float* out = (float*)d_out;

  float* w = (float*)d_ws;
  const size_t M1 = 1048576;
  int* z1f = (int*)w;                      // 3M ints: [branch][hi .5M | lo .5M]
  int* z2f = (int*)(w + 3 * M1);           // 3M ints
  float* fout = w + 6 * M1;                // 1M fp32
  float* u = w + 7 * M1;                   // 8M fp32
  int* Afx = (int*)u;                      // 8M ints (hi 4M | lo 4M); dead pre-convup
  int* Afy = (int*)(w + 3 * M1);           // 4M ints over z2f+fout; dead pre-conv2
  int* Qf = (int*)(w + 15 * M1);
  int* Kf = Qf + 524288;
  int* Vf = Kf + 524288;
  float* stats = (float*)(Vf + 524288);    // 1792 floats
  int* wt1f = (int*)(stats + 1792);        // 81920 ints
  int* wt2f = wt1f + 81920;                // 12288 ints
  float* biasf = (float*)(wt2f + 12288);   // 192 floats
  float* wut = biasf + 192;                // 32768 floats

  hipMemsetAsync(stats, 0, 1792 * sizeof(float), stream);

  prep1_k<<<dim3(160), dim3(256), 0, stream>>>(ws1, wx1, wy1, wt1f);
  packA_k<<<dim3(4096, 2), dim3(256), 0, stream>>>(x, y, Afx, Afy);
  conv1_k<<<dim3(256, 3), dim3(64), 0, stream>>>(Afx, Afy, wt1f, z1f, stats);
  prep2_k<<<dim3(3), dim3(256), 0, stream>>>(ws2, wx2, wy2, gs1, bs1, gx1, bx1,
                                             gy1, by1, stats, wt2f, biasf);
  conv2_k<<<dim3(256, 3), dim3(64), 0, stream>>>(z1f, wt2f, biasf, z2f, stats);
  prepu_k<<<dim3(128), dim3(256), 0, stream>>>(wu, wut);
  pack_k<<<dim3(2048, 1, 3), dim3(256), 0, stream>>>(z2f, gs2, bs2, gx2, bx2, gy2,
                                                     by2, Qf, Kf, Vf, stats);
  attn_k<<<dim3(1024), dim3(256), 0, stream>>>(Qf, Kf, Vf, fout);
  convup_k<<<dim3(64, 8), dim3(256), 0, stream>>>(fout, wut, u, stats);
  final_k<<<dim3(32768), dim3(256), 0, stream>>>(x, u, gu, bu, stats, out);
}